// Round 1
// baseline (201.581 us; speedup 1.0000x reference)
//
#include <hip/hip_runtime.h>

// RandomShiftsAug: out[n,c,h,w] = x[n,c, clamp(h+sy-4,0,83), clamp(w+sx-4,0,83)]
// N=1024, C=4, H=W=84, PAD=4, shift in [0,8] per (n, {x,y}).
// The reference's bilinear sampling has exactly-integer sample coords, so it
// reduces to an edge-clamped integer gather.

#define N_IMG 1024
#define C_DIM 4
#define HW 84
#define PADV 4
#define WQ 21            // 84 / 4 float4s per row
#define IMG_ELEMS (C_DIM * HW * HW)      // 28224 floats per image
#define IMG_VEC4 (IMG_ELEMS / 4)         // 7056 float4 per image
#define TOTAL_VEC4 (N_IMG * IMG_VEC4)    // 7,225,344

__global__ __launch_bounds__(256)
void shift_aug_kernel(const float* __restrict__ x,
                      const int* __restrict__ shift,
                      float* __restrict__ out) {
    int idx4 = blockIdx.x * blockDim.x + threadIdx.x;
    if (idx4 >= TOTAL_VEC4) return;

    int n  = idx4 / IMG_VEC4;
    int r  = idx4 - n * IMG_VEC4;     // within image: (c*84 + h)*21 + wq
    int wq = r % WQ;
    int t  = r / WQ;                  // c*84 + h
    int h  = t % HW;

    int sx = shift[2 * n]     - PADV;
    int sy = shift[2 * n + 1] - PADV;

    int sh = min(max(h + sy, 0), HW - 1);

    // source row: image n, channel c (= t/84), row sh
    const float* __restrict__ row =
        x + (size_t)n * IMG_ELEMS + (size_t)(t - h + sh) * HW;

    int wb = wq * 4 + sx;             // source column of lane's first pixel

    float4 v;
    if (wb >= 0 && wb + 3 <= HW - 1) {
        // interior: 4 contiguous in-bounds reads
        v.x = row[wb + 0];
        v.y = row[wb + 1];
        v.z = row[wb + 2];
        v.w = row[wb + 3];
    } else {
        v.x = row[min(max(wb + 0, 0), HW - 1)];
        v.y = row[min(max(wb + 1, 0), HW - 1)];
        v.z = row[min(max(wb + 2, 0), HW - 1)];
        v.w = row[min(max(wb + 3, 0), HW - 1)];
    }

    reinterpret_cast<float4*>(out)[idx4] = v;
}

extern "C" void kernel_launch(void* const* d_in, const int* in_sizes, int n_in,
                              void* d_out, int out_size, void* d_ws, size_t ws_size,
                              hipStream_t stream) {
    const float* x     = (const float*)d_in[0];
    const int*   shift = (const int*)d_in[1];
    float*       out   = (float*)d_out;

    const int threads = 256;
    const int blocks  = (TOTAL_VEC4 + threads - 1) / threads;  // 28224
    shift_aug_kernel<<<blocks, threads, 0, stream>>>(x, shift, out);
}

// Round 2
// 197.850 us; speedup vs baseline: 1.0189x; 1.0189x over previous
//
#include <hip/hip_runtime.h>

// RandomShiftsAug: out[n,c,h,w] = x[n,c, clamp(h+sy-4,0,83), clamp(w+sx-4,0,83)]
// N=1024, C=4, H=W=84, PAD=4, shift in [0,8] per (n, {x,y}).
// The reference's bilinear sampling has exactly-integer sample coords, so it
// reduces to an edge-clamped integer gather.
//
// R1 -> R2: replace 4 scalar loads with ONE global_load_dwordx4 at a
// dword-aligned address (aligned(4) vector type forces clang to emit a single
// dwordx4 — CDNA global multi-dword loads need only 4B alignment). Cuts VMEM
// instructions per thread from 5 to 2, matching the float4-copy pattern that
// achieves 6.29 TB/s on this chip.

#define N_IMG 1024
#define C_DIM 4
#define HW 84
#define PADV 4
#define WQ 21            // 84 / 4 float4s per row
#define IMG_ELEMS (C_DIM * HW * HW)      // 28224 floats per image
#define IMG_VEC4 (IMG_ELEMS / 4)         // 7056 float4 per image
#define TOTAL_VEC4 (N_IMG * IMG_VEC4)    // 7,225,344

typedef float vfloat4 __attribute__((ext_vector_type(4)));
typedef vfloat4 uvfloat4 __attribute__((aligned(4)));   // 4B-aligned float4

__global__ __launch_bounds__(256)
void shift_aug_kernel(const float* __restrict__ x,
                      const int* __restrict__ shift,
                      float* __restrict__ out) {
    unsigned idx4 = blockIdx.x * blockDim.x + threadIdx.x;
    if (idx4 >= TOTAL_VEC4) return;

    unsigned n  = idx4 / IMG_VEC4;
    unsigned r  = idx4 - n * IMG_VEC4;    // within image: (c*84 + h)*21 + wq
    unsigned wq = r % WQ;
    unsigned t  = r / WQ;                 // c*84 + h
    unsigned h  = t % HW;

    int sx = shift[2 * n]     - PADV;
    int sy = shift[2 * n + 1] - PADV;

    int sh = min(max((int)h + sy, 0), HW - 1);

    // source row: image n, channel c (= t/84), row sh
    const float* __restrict__ row =
        x + (size_t)n * IMG_ELEMS + (size_t)((int)t - (int)h + sh) * HW;

    int wb = (int)wq * 4 + sx;            // source column of lane's first pixel

    vfloat4 v;
    if (wb >= 0 && wb <= HW - 4) {
        // interior: one dwordx4 load (dword-aligned is sufficient on CDNA)
        v = *(const uvfloat4*)(row + wb);
    } else {
        v.x = row[min(max(wb + 0, 0), HW - 1)];
        v.y = row[min(max(wb + 1, 0), HW - 1)];
        v.z = row[min(max(wb + 2, 0), HW - 1)];
        v.w = row[min(max(wb + 3, 0), HW - 1)];
    }

    *reinterpret_cast<vfloat4*>(out + (size_t)idx4 * 4) = v;
}

extern "C" void kernel_launch(void* const* d_in, const int* in_sizes, int n_in,
                              void* d_out, int out_size, void* d_ws, size_t ws_size,
                              hipStream_t stream) {
    const float* x     = (const float*)d_in[0];
    const int*   shift = (const int*)d_in[1];
    float*       out   = (float*)d_out;

    const int threads = 256;
    const int blocks  = (TOTAL_VEC4 + threads - 1) / threads;  // 28224
    shift_aug_kernel<<<blocks, threads, 0, stream>>>(x, shift, out);
}

// Round 3
// 197.351 us; speedup vs baseline: 1.0214x; 1.0025x over previous
//
#include <hip/hip_runtime.h>

// RandomShiftsAug: out[n,c,h,w] = x[n,c, clamp(h+sy-4,0,83), clamp(w+sx-4,0,83)]
// N=1024, C=4, H=W=84, PAD=4, shift in [0,8] per (n, {x,y}).
// The reference's bilinear sampling has exactly-integer sample coords, so it
// reduces to an edge-clamped integer gather.
//
// R2 -> R3: BRANCHLESS clamp. The R2 boundary branch diverged (~3 lanes/wave),
// so each wave issued the vector load AND the 4 scalar clamp loads (6 VMEM
// instr/wave). Now: one dwordx4 from clamped base b=clamp(wb,0,80) (always
// in-bounds, 4B-aligned), then per-element register select
// v[j] = L[clamp(wb+j,0,83)-b] via cndmask chain (rel==j for interior lanes).
// Every thread: exactly 1 load_dwordx4 + 1 store_dwordx4 — the 6.3 TB/s copy
// pattern. Shift pair loaded as one int2.

#define N_IMG 1024
#define C_DIM 4
#define HW 84
#define PADV 4
#define WQ 21            // 84 / 4 float4s per row
#define IMG_ELEMS (C_DIM * HW * HW)      // 28224 floats per image
#define IMG_VEC4 (IMG_ELEMS / 4)         // 7056 float4 per image
#define TOTAL_VEC4 (N_IMG * IMG_VEC4)    // 7,225,344

typedef float vfloat4 __attribute__((ext_vector_type(4)));
typedef vfloat4 uvfloat4 __attribute__((aligned(4)));   // 4B-aligned float4

__device__ __forceinline__ float pick4(vfloat4 L, int rel) {
    float r = L.x;
    r = (rel == 1) ? L.y : r;
    r = (rel == 2) ? L.z : r;
    r = (rel == 3) ? L.w : r;
    return r;
}

__global__ __launch_bounds__(256)
void shift_aug_kernel(const float* __restrict__ x,
                      const int* __restrict__ shift,
                      float* __restrict__ out) {
    unsigned idx4 = blockIdx.x * blockDim.x + threadIdx.x;
    if (idx4 >= TOTAL_VEC4) return;

    unsigned n  = idx4 / IMG_VEC4;
    unsigned r  = idx4 - n * IMG_VEC4;    // within image: (c*84 + h)*21 + wq
    unsigned wq = r % WQ;
    unsigned t  = r / WQ;                 // c*84 + h
    unsigned h  = t % HW;

    int2 s = ((const int2*)shift)[n];     // one dwordx2
    int sx = s.x - PADV;
    int sy = s.y - PADV;

    int sh = min(max((int)h + sy, 0), HW - 1);

    // source row: image n, channel c (= t/84), row sh
    const float* __restrict__ row =
        x + (size_t)n * IMG_ELEMS + (size_t)((int)t - (int)h + sh) * HW;

    int wb = (int)wq * 4 + sx;            // source column of lane's first pixel
    int b  = min(max(wb, 0), HW - 4);     // clamped load base, always in-bounds

    vfloat4 L = *(const uvfloat4*)(row + b);   // single dwordx4 (4B-aligned ok)

    vfloat4 v;
    v.x = pick4(L, min(max(wb + 0, 0), HW - 1) - b);
    v.y = pick4(L, min(max(wb + 1, 0), HW - 1) - b);
    v.z = pick4(L, min(max(wb + 2, 0), HW - 1) - b);
    v.w = pick4(L, min(max(wb + 3, 0), HW - 1) - b);

    *reinterpret_cast<vfloat4*>(out + (size_t)idx4 * 4) = v;
}

extern "C" void kernel_launch(void* const* d_in, const int* in_sizes, int n_in,
                              void* d_out, int out_size, void* d_ws, size_t ws_size,
                              hipStream_t stream) {
    const float* x     = (const float*)d_in[0];
    const int*   shift = (const int*)d_in[1];
    float*       out   = (float*)d_out;

    const int threads = 256;
    const int blocks  = (TOTAL_VEC4 + threads - 1) / threads;  // 28224
    shift_aug_kernel<<<blocks, threads, 0, stream>>>(x, shift, out);
}

// Round 4
// 195.455 us; speedup vs baseline: 1.0313x; 1.0097x over previous
//
#include <hip/hip_runtime.h>

// RandomShiftsAug: out[n,c,h,w] = x[n,c, clamp(h+sy-4,0,83), clamp(w+sx-4,0,83)]
// N=1024, C=4, H=W=84, PAD=4, shift in [0,8] per (n, {x,y}).
// Reference's bilinear sample coords are exactly integer -> edge-clamped gather.
//
// R3 -> R4: LDS-staged, all-scalar addressing.
//   Evidence: R1/R2/R3 (5-VMEM branchy / vector+fallback / branchless
//   misaligned) ALL land ~73us at 2.4 TB/s with VALUBusy 16% -> neither VMEM
//   count, alignment, nor VALU was the bound. Remaining suspects: per-lane
//   dependent shift gather + div/mod addressing + unpipelined read shape.
//   This version: n=blockIdx.y, c/band from blockIdx.x (scalar, no div/mod on
//   lanes; shift load becomes uniform s_load). Block (21,12) stages 12 clamped
//   source rows to LDS via ALIGNED coalesced float4 loads, applies the column
//   shift from LDS (clamped ds_read_b32, misalignment cheap there), stores
//   aligned float4. 2 VMEM/thread, both aligned+coalesced.

#define HW 84
#define WQ 21                 // 84/4 float4 per row
#define RPB 12                // rows per block; 84 = 7*12
#define PADV 4
#define PLANE (HW * HW)       // 7056 floats per (n,c) plane
#define IMG_ELEMS (4 * PLANE) // 28224 floats per image

__global__ __launch_bounds__(WQ * RPB)   // 252 threads
void shift_aug_kernel(const float* __restrict__ x,
                      const int* __restrict__ shift,
                      float* __restrict__ out) {
    __shared__ float lds[RPB][HW];

    const int tx = threadIdx.x;   // [0,21) : float4 index within row
    const int ty = threadIdx.y;   // [0,12) : row within band
    const int bx = blockIdx.x;    // [0,28) : (c, band)
    const int n  = blockIdx.y;    // [0,1024)

    const int c    = bx / 7;            // scalar
    const int band = (bx - c * 7) * RPB; // scalar

    // uniform address -> s_load_dwordx2; sx,sy live in SGPRs
    const int sx = shift[2 * n]     - PADV;
    const int sy = shift[2 * n + 1] - PADV;

    const int h  = band + ty;
    const int sh = min(max(h + sy, 0), HW - 1);   // clamped source row

    const float* __restrict__ plane = x + (size_t)n * IMG_ELEMS + (size_t)c * PLANE;

    // Stage source row sh: 21 lanes x 16B aligned, block reads ~4KB contiguous.
    float4 L = ((const float4*)(plane + sh * HW))[tx];
    ((float4*)&lds[ty][0])[tx] = L;
    __syncthreads();

    // Column shift + edge clamp out of LDS.
    const int wb = 4 * tx + sx;
    float4 v;
    v.x = lds[ty][min(max(wb + 0, 0), HW - 1)];
    v.y = lds[ty][min(max(wb + 1, 0), HW - 1)];
    v.z = lds[ty][min(max(wb + 2, 0), HW - 1)];
    v.w = lds[ty][min(max(wb + 3, 0), HW - 1)];

    float* __restrict__ oplane = out + (size_t)n * IMG_ELEMS + (size_t)c * PLANE;
    ((float4*)(oplane + h * HW))[tx] = v;
}

extern "C" void kernel_launch(void* const* d_in, const int* in_sizes, int n_in,
                              void* d_out, int out_size, void* d_ws, size_t ws_size,
                              hipStream_t stream) {
    const float* x     = (const float*)d_in[0];
    const int*   shift = (const int*)d_in[1];
    float*       out   = (float*)d_out;

    dim3 block(WQ, RPB, 1);        // 252 threads
    dim3 grid(28, 1024, 1);        // (c,band) x n
    shift_aug_kernel<<<grid, block, 0, stream>>>(x, shift, out);
}